// Round 5
// baseline (202.571 us; speedup 1.0000x reference)
//
#include <hip/hip_runtime.h>
#include <cstddef>

#define HH 224
#define WW 608
#define HWSZ (HH * WW)

__device__ __forceinline__ float lrelu(float v) { return v > 0.0f ? v : 0.01f * v; }

// Dual CondMul: two independent pixels' chains interleaved at the FMA-step
// granularity so chain B's loads/FMAs hide chain A's load latency.
// Weight layout [i=0..31][o=0..CO-1] (pointers already offset by gather index).
// Activations distributed 8/lane across the 4-lane group; accumulate i ascending
// per output with bias added last — bit-identical to the reference order.
template <int CO>
__device__ __forceinline__ void cm4_dual(const float* __restrict__ wA, const float* __restrict__ bA,
                                         const float* __restrict__ wB, const float* __restrict__ bB,
                                         int s,
                                         const float (&actA)[8], const float (&actB)[8],
                                         float (&accA)[CO / 4], float (&accB)[CO / 4]) {
    constexpr int CH = CO / 4;
#pragma unroll
    for (int j = 0; j < CH; j++) { accA[j] = 0.0f; accB[j] = 0.0f; }
#pragma unroll
    for (int sp = 0; sp < 4; sp++) {
#pragma unroll
        for (int ii = 0; ii < 8; ii++) {
            float xa = __shfl(actA[ii], sp, 4);     // compile-time sp -> DPP broadcast
            float xb = __shfl(actB[ii], sp, 4);
            const float* ra = wA + (sp * 8 + ii) * CO + s * CH;
            const float* rb = wB + (sp * 8 + ii) * CO + s * CH;
            if constexpr (CH == 8) {
                float4 a0 = *reinterpret_cast<const float4*>(ra);
                float4 a1 = *reinterpret_cast<const float4*>(ra + 4);
                float4 b0 = *reinterpret_cast<const float4*>(rb);
                float4 b1 = *reinterpret_cast<const float4*>(rb + 4);
                accA[0] = fmaf(xa, a0.x, accA[0]); accA[1] = fmaf(xa, a0.y, accA[1]);
                accA[2] = fmaf(xa, a0.z, accA[2]); accA[3] = fmaf(xa, a0.w, accA[3]);
                accA[4] = fmaf(xa, a1.x, accA[4]); accA[5] = fmaf(xa, a1.y, accA[5]);
                accA[6] = fmaf(xa, a1.z, accA[6]); accA[7] = fmaf(xa, a1.w, accA[7]);
                accB[0] = fmaf(xb, b0.x, accB[0]); accB[1] = fmaf(xb, b0.y, accB[1]);
                accB[2] = fmaf(xb, b0.z, accB[2]); accB[3] = fmaf(xb, b0.w, accB[3]);
                accB[4] = fmaf(xb, b1.x, accB[4]); accB[5] = fmaf(xb, b1.y, accB[5]);
                accB[6] = fmaf(xb, b1.z, accB[6]); accB[7] = fmaf(xb, b1.w, accB[7]);
            } else {
                float4 a0 = *reinterpret_cast<const float4*>(ra);
                float4 b0 = *reinterpret_cast<const float4*>(rb);
                accA[0] = fmaf(xa, a0.x, accA[0]); accA[1] = fmaf(xa, a0.y, accA[1]);
                accA[2] = fmaf(xa, a0.z, accA[2]); accA[3] = fmaf(xa, a0.w, accA[3]);
                accB[0] = fmaf(xb, b0.x, accB[0]); accB[1] = fmaf(xb, b0.y, accB[1]);
                accB[2] = fmaf(xb, b0.z, accB[2]); accB[3] = fmaf(xb, b0.w, accB[3]);
            }
        }
    }
#pragma unroll
    for (int j = 0; j < CH; j++) { accA[j] += bA[s * CH + j]; accB[j] += bB[s * CH + j]; }
}

__device__ __forceinline__ void wb_lrelu8(float (&act)[8], const float (&acc)[8]) {
#pragma unroll
    for (int j = 0; j < 8; j++) act[j] = lrelu(acc[j]);
}

// First-max argmax over 16 values distributed 4-per-lane across the 4-lane group.
__device__ __forceinline__ int argmax4(const float (&v)[4], int s) {
    float bv = v[0];
    int bi = 4 * s;
#pragma unroll
    for (int j = 1; j < 4; j++) {
        if (v[j] > bv) { bv = v[j]; bi = 4 * s + j; }
    }
#pragma unroll
    for (int m = 1; m <= 2; m <<= 1) {
        float ov = __shfl_xor(bv, m, 4);
        int oi = __shfl_xor(bi, m, 4);
        if (ov > bv || (ov == bv && oi < bi)) { bv = ov; bi = oi; }
    }
    return bi;   // all 4 lanes converge to (max value, lowest index)
}

extern "C" __global__ __launch_bounds__(256, 4)
void regressor_fused(const float* __restrict__ x_in,
                     const float* __restrict__ w1_0, const float* __restrict__ b1_0,
                     const float* __restrict__ w1_1, const float* __restrict__ b1_1,
                     const float* __restrict__ w1_2, const float* __restrict__ b1_2,
                     const float* __restrict__ w2_0, const float* __restrict__ b2_0,
                     const float* __restrict__ w2_1, const float* __restrict__ b2_1,
                     const float* __restrict__ w2_2, const float* __restrict__ b2_2,
                     const float* __restrict__ w3_0, const float* __restrict__ b3_0,
                     const float* __restrict__ w3_1, const float* __restrict__ b3_1,
                     const float* __restrict__ w3_2, const float* __restrict__ b3_2,
                     const float* __restrict__ wr0, const float* __restrict__ br0,
                     const float* __restrict__ wr1, const float* __restrict__ br1,
                     float* __restrict__ out) {
    // XCD line-grouping swizzle: all 5 blocks of a line share bid%8 -> same XCD.
    const int bid = blockIdx.x;
    const int r = bid & 7;
    const int t = bid >> 3;
    const int xblk = t % 5;
    const int g = t / 5;
    const int h = 8 * g + r;

    const int tid = threadIdx.x;
    const int slot = tid >> 2;        // 0..63
    const int s = tid & 3;            // sub-lane within pixel group
    const int wA = xblk * 128 + slot;          // always < 608 (max 575)
    const int wB = xblk * 128 + 64 + slot;     // may exceed 607 in last block
    const bool validB = (wB < WW);
    const int wBc = validB ? wB : (WW - 1);
    const int baseA = h * WW + wA;
    const int baseB = h * WW + wBc;

    // ---- stage-1 per-line weights, staged transposed to [i][o] in LDS ----
    __shared__ __align__(16) float sW0[1024];
    __shared__ __align__(16) float sW1[1024];
    __shared__ __align__(16) float sW2[512];
    for (int tt = tid; tt < 1024; tt += 256) {
        int i = tt >> 5, o = tt & 31;
        sW0[tt] = w1_0[h * 1024 + o * 32 + i];
        sW1[tt] = w1_1[h * 1024 + o * 32 + i];
    }
    for (int tt = tid; tt < 512; tt += 256) {
        int i = tt >> 4, o = tt & 15;
        sW2[tt] = w1_2[h * 512 + o * 32 + i];
    }
    __syncthreads();

    float actA[8], actB[8], accA[8], accB[8], ac4A[4], ac4B[4];

    // ---------------- stage 1: per-line MLP -> class1 ----------------
#pragma unroll
    for (int ii = 0; ii < 8; ii++) {
        actA[ii] = x_in[(8 * s + ii) * HWSZ + baseA];
        actB[ii] = x_in[(8 * s + ii) * HWSZ + baseB];
    }
    cm4_dual<32>(sW0, b1_0 + h * 32, sW0, b1_0 + h * 32, s, actA, actB, accA, accB);
    wb_lrelu8(actA, accA); wb_lrelu8(actB, accB);
    cm4_dual<32>(sW1, b1_1 + h * 32, sW1, b1_1 + h * 32, s, actA, actB, accA, accB);
    wb_lrelu8(actA, accA); wb_lrelu8(actB, accB);
    cm4_dual<16>(sW2, b1_2 + h * 16, sW2, b1_2 + h * 16, s, actA, actB, ac4A, ac4B);
    const int i1A = argmax4(ac4A, s);
    const int i1B = argmax4(ac4B, s);

    // ---------------- stage 2: CondMul on (line, class1) ----------------
#pragma unroll
    for (int ii = 0; ii < 8; ii++) {
        actA[ii] = x_in[(32 + 8 * s + ii) * HWSZ + baseA];
        actB[ii] = x_in[(32 + 8 * s + ii) * HWSZ + baseB];
    }
    const size_t i2A_ = (size_t)h * 16 + (size_t)i1A;
    const size_t i2B_ = (size_t)h * 16 + (size_t)i1B;
    cm4_dual<32>(w2_0 + i2A_ * 1024, b2_0 + i2A_ * 32, w2_0 + i2B_ * 1024, b2_0 + i2B_ * 32,
                 s, actA, actB, accA, accB);
    wb_lrelu8(actA, accA); wb_lrelu8(actB, accB);
    cm4_dual<32>(w2_1 + i2A_ * 1024, b2_1 + i2A_ * 32, w2_1 + i2B_ * 1024, b2_1 + i2B_ * 32,
                 s, actA, actB, accA, accB);
    wb_lrelu8(actA, accA); wb_lrelu8(actB, accB);
    cm4_dual<16>(w2_2 + i2A_ * 512, b2_2 + i2A_ * 16, w2_2 + i2B_ * 512, b2_2 + i2B_ * 16,
                 s, actA, actB, ac4A, ac4B);
    const int i2A = argmax4(ac4A, s);
    const int i2B = argmax4(ac4B, s);

    const int inds12A = i1A * 12 + (i2A - 2);
    const int inds12B = i1B * 12 + (i2B - 2);
    const size_t i3A_ = (size_t)h * 192 + (size_t)min(max(inds12A, 0), 191);
    const size_t i3B_ = (size_t)h * 192 + (size_t)min(max(inds12B, 0), 191);

    // ---------------- stage 3: CondMul on (line, class12) ----------------
#pragma unroll
    for (int ii = 0; ii < 8; ii++) {
        actA[ii] = x_in[(64 + 8 * s + ii) * HWSZ + baseA];
        actB[ii] = x_in[(64 + 8 * s + ii) * HWSZ + baseB];
    }
    cm4_dual<32>(w3_0 + i3A_ * 1024, b3_0 + i3A_ * 32, w3_0 + i3B_ * 1024, b3_0 + i3B_ * 32,
                 s, actA, actB, accA, accB);
    wb_lrelu8(actA, accA); wb_lrelu8(actB, accB);
    cm4_dual<32>(w3_1 + i3A_ * 1024, b3_1 + i3A_ * 32, w3_1 + i3B_ * 1024, b3_1 + i3B_ * 32,
                 s, actA, actB, accA, accB);
    wb_lrelu8(actA, accA); wb_lrelu8(actB, accB);
    cm4_dual<16>(w3_2 + i3A_ * 512, b3_2 + i3A_ * 16, w3_2 + i3B_ * 512, b3_2 + i3B_ * 16,
                 s, actA, actB, ac4A, ac4B);
    const int i3A = argmax4(ac4A, s);
    const int i3B = argmax4(ac4B, s);

    const int leafA = min(max(inds12A * 10 + (i3A - 3), 0), 1919);
    const int leafB = min(max(inds12B * 10 + (i3B - 3), 0), 1919);

    // ---------------- regressor at predicted leaf ----------------
#pragma unroll
    for (int ii = 0; ii < 8; ii++) {
        actA[ii] = x_in[(96 + 8 * s + ii) * HWSZ + baseA];
        actB[ii] = x_in[(96 + 8 * s + ii) * HWSZ + baseB];
    }
    const size_t isA = (size_t)h * 384 + (size_t)(leafA / 5);
    const size_t isB = (size_t)h * 384 + (size_t)(leafB / 5);
    cm4_dual<32>(wr0 + isA * 1024, br0 + isA * 32, wr0 + isB * 1024, br0 + isB * 32,
                 s, actA, actB, accA, accB);
    wb_lrelu8(actA, accA); wb_lrelu8(actB, accB);

    const size_t irA = (size_t)h * 1920 + (size_t)leafA;
    const size_t irB = (size_t)h * 1920 + (size_t)leafB;
    const float* ra = wr1 + irA * 32 + 8 * s;
    const float* rb = wr1 + irB * 32 + 8 * s;
    float4 wa0 = *reinterpret_cast<const float4*>(ra);
    float4 wa1 = *reinterpret_cast<const float4*>(ra + 4);
    float4 wb0 = *reinterpret_cast<const float4*>(rb);
    float4 wb1 = *reinterpret_cast<const float4*>(rb + 4);
    float rpA = 0.0f, rpB = 0.0f;
    rpA = fmaf(actA[0], wa0.x, rpA); rpA = fmaf(actA[1], wa0.y, rpA);
    rpA = fmaf(actA[2], wa0.z, rpA); rpA = fmaf(actA[3], wa0.w, rpA);
    rpA = fmaf(actA[4], wa1.x, rpA); rpA = fmaf(actA[5], wa1.y, rpA);
    rpA = fmaf(actA[6], wa1.z, rpA); rpA = fmaf(actA[7], wa1.w, rpA);
    rpB = fmaf(actB[0], wb0.x, rpB); rpB = fmaf(actB[1], wb0.y, rpB);
    rpB = fmaf(actB[2], wb0.z, rpB); rpB = fmaf(actB[3], wb0.w, rpB);
    rpB = fmaf(actB[4], wb1.x, rpB); rpB = fmaf(actB[5], wb1.y, rpB);
    rpB = fmaf(actB[6], wb1.z, rpB); rpB = fmaf(actB[7], wb1.w, rpB);
    rpA += __shfl_xor(rpA, 1, 4);
    rpA += __shfl_xor(rpA, 2, 4);
    rpB += __shfl_xor(rpB, 1, 4);
    rpB += __shfl_xor(rpB, 2, 4);
    const float rA = rpA + br1[irA];
    const float rB = rpB + br1[irB];

    if (s == 0) {
        float vA = ((float)leafA + rA) * (1.0f / 1920.0f);
        out[baseA] = (vA - 0.1f) * 1.25f;
        if (validB) {
            float vB = ((float)leafB + rB) * (1.0f / 1920.0f);
            out[h * WW + wB] = (vB - 0.1f) * 1.25f;
        }
    }
}

extern "C" void kernel_launch(void* const* d_in, const int* in_sizes, int n_in,
                              void* d_out, int out_size, void* d_ws, size_t ws_size,
                              hipStream_t stream) {
    const float* p[23];
    for (int i = 0; i < 23; i++) p[i] = (const float*)d_in[i];
    regressor_fused<<<dim3(1120), 256, 0, stream>>>(
        p[0],
        p[1], p[2], p[3], p[4], p[5], p[6],
        p[7], p[8], p[9], p[10], p[11], p[12],
        p[13], p[14], p[15], p[16], p[17], p[18],
        p[19], p[20], p[21], p[22],
        (float*)d_out);
}

// Round 6
// 134.935 us; speedup vs baseline: 1.5012x; 1.5012x over previous
//
#include <hip/hip_runtime.h>
#include <cstddef>

#define HH 224
#define WW 608
#define HWSZ (HH * WW)

__device__ __forceinline__ float lrelu(float v) { return v > 0.0f ? v : 0.01f * v; }

// CondMul, output dim split across a 4-lane group (sub-lane s), with an explicit
// 2-deep software pipeline over 4-step chunks: chunk c+1's weight rows are issued
// before chunk c's FMAs consume buffer c, guaranteeing ~8 float4 loads in flight
// independent of compiler scheduling heuristics.
// Weight layout [i=0..31][o=0..CO-1] (wmat already offset by the gather index).
// Activations distributed 8/lane; lane sp holds act[ii] = x[8*sp+ii].
// Accumulation: i ascending per output, bias last — matches reference order.
template <int CO>
__device__ __forceinline__ void cm4p(const float* __restrict__ wmat,
                                     const float* __restrict__ bvec,
                                     int s, const float (&act)[8], float (&acc)[CO / 4]) {
    constexpr int CH = CO / 4;           // outputs per lane (8 or 4)
    constexpr int NV = CH / 4;           // float4 loads per step (2 or 1)
    const float* __restrict__ base = wmat + s * CH;
    float4 buf[2][4 * NV];               // all indices compile-time after unroll

    // prologue: chunk 0 (steps 0..3)
#pragma unroll
    for (int st = 0; st < 4; st++)
#pragma unroll
        for (int v = 0; v < NV; v++)
            buf[0][st * NV + v] =
                *reinterpret_cast<const float4*>(base + st * CO + 4 * v);

#pragma unroll
    for (int j = 0; j < CH; j++) acc[j] = 0.0f;

#pragma unroll
    for (int c = 0; c < 8; c++) {        // fully unrolled -> cur/next compile-time
        const int cur = c & 1;
        if (c < 7) {                     // issue next chunk's loads first
#pragma unroll
            for (int st = 0; st < 4; st++)
#pragma unroll
                for (int v = 0; v < NV; v++)
                    buf[cur ^ 1][st * NV + v] = *reinterpret_cast<const float4*>(
                        base + ((c + 1) * 4 + st) * CO + 4 * v);
        }
#pragma unroll
        for (int st = 0; st < 4; st++) { // consume current chunk
            const int i = c * 4 + st;    // global k-step: sp = i>>3, ii = i&7
            const float xi = __shfl(act[i & 7], i >> 3, 4);
#pragma unroll
            for (int v = 0; v < NV; v++) {
                float4 t = buf[cur][st * NV + v];
                acc[4 * v + 0] = fmaf(xi, t.x, acc[4 * v + 0]);
                acc[4 * v + 1] = fmaf(xi, t.y, acc[4 * v + 1]);
                acc[4 * v + 2] = fmaf(xi, t.z, acc[4 * v + 2]);
                acc[4 * v + 3] = fmaf(xi, t.w, acc[4 * v + 3]);
            }
        }
    }
#pragma unroll
    for (int j = 0; j < CH; j++) acc[j] += bvec[s * CH + j];
}

__device__ __forceinline__ void wb_lrelu8(float (&act)[8], const float (&acc)[8]) {
#pragma unroll
    for (int j = 0; j < 8; j++) act[j] = lrelu(acc[j]);
}

// First-max argmax over 16 values distributed 4-per-lane across the 4-lane group.
__device__ __forceinline__ int argmax4(const float (&v)[4], int s) {
    float bv = v[0];
    int bi = 4 * s;
#pragma unroll
    for (int j = 1; j < 4; j++) {
        if (v[j] > bv) { bv = v[j]; bi = 4 * s + j; }
    }
#pragma unroll
    for (int m = 1; m <= 2; m <<= 1) {
        float ov = __shfl_xor(bv, m, 4);
        int oi = __shfl_xor(bi, m, 4);
        if (ov > bv || (ov == bv && oi < bi)) { bv = ov; bi = oi; }
    }
    return bi;   // all 4 lanes converge to (max value, lowest index)
}

extern "C" __global__ __launch_bounds__(256, 3)
void regressor_fused(const float* __restrict__ x_in,
                     const float* __restrict__ w1_0, const float* __restrict__ b1_0,
                     const float* __restrict__ w1_1, const float* __restrict__ b1_1,
                     const float* __restrict__ w1_2, const float* __restrict__ b1_2,
                     const float* __restrict__ w2_0, const float* __restrict__ b2_0,
                     const float* __restrict__ w2_1, const float* __restrict__ b2_1,
                     const float* __restrict__ w2_2, const float* __restrict__ b2_2,
                     const float* __restrict__ w3_0, const float* __restrict__ b3_0,
                     const float* __restrict__ w3_1, const float* __restrict__ b3_1,
                     const float* __restrict__ w3_2, const float* __restrict__ b3_2,
                     const float* __restrict__ wr0, const float* __restrict__ br0,
                     const float* __restrict__ wr1, const float* __restrict__ br1,
                     float* __restrict__ out) {
    const int h = blockIdx.y;
    const int tid = threadIdx.x;
    const int p = tid >> 2;          // pixel within block (0..63)
    const int s = tid & 3;           // output-chunk sub-lane (0..3)
    const int w = blockIdx.x * 64 + p;
    const bool valid = (w < WW);
    const int wc = valid ? w : (WW - 1);   // tail lanes compute a duplicate pixel
    const int base = h * WW + wc;

    // ---- stage-1 per-line weights, staged transposed to [i][o] in LDS ----
    __shared__ __align__(16) float sW0[1024];
    __shared__ __align__(16) float sW1[1024];
    __shared__ __align__(16) float sW2[512];
    for (int tt = tid; tt < 1024; tt += 256) {
        int i = tt >> 5, o = tt & 31;
        sW0[tt] = w1_0[h * 1024 + o * 32 + i];
        sW1[tt] = w1_1[h * 1024 + o * 32 + i];
    }
    for (int tt = tid; tt < 512; tt += 256) {
        int i = tt >> 4, o = tt & 15;
        sW2[tt] = w1_2[h * 512 + o * 32 + i];
    }
    __syncthreads();

    float act[8], acc8[8], acc4[4];

    // ---------------- stage 1: per-line MLP -> class1 ----------------
#pragma unroll
    for (int ii = 0; ii < 8; ii++) act[ii] = x_in[(8 * s + ii) * HWSZ + base];
    cm4p<32>(sW0, b1_0 + h * 32, s, act, acc8);
    wb_lrelu8(act, acc8);
    cm4p<32>(sW1, b1_1 + h * 32, s, act, acc8);
    wb_lrelu8(act, acc8);
    cm4p<16>(sW2, b1_2 + h * 16, s, act, acc4);
    const int i1 = argmax4(acc4, s);

    // ---------------- stage 2: CondMul on (line, class1) ----------------
#pragma unroll
    for (int ii = 0; ii < 8; ii++) act[ii] = x_in[(32 + 8 * s + ii) * HWSZ + base];
    const size_t idx2 = (size_t)h * 16 + (size_t)i1;
    cm4p<32>(w2_0 + idx2 * 1024, b2_0 + idx2 * 32, s, act, acc8);
    wb_lrelu8(act, acc8);
    cm4p<32>(w2_1 + idx2 * 1024, b2_1 + idx2 * 32, s, act, acc8);
    wb_lrelu8(act, acc8);
    cm4p<16>(w2_2 + idx2 * 512, b2_2 + idx2 * 16, s, act, acc4);
    const int i2 = argmax4(acc4, s);

    const int inds12 = i1 * 12 + (i2 - 2);               // unclipped (used below)
    const int c12 = min(max(inds12, 0), 191);
    const size_t idx3 = (size_t)h * 192 + (size_t)c12;

    // ---------------- stage 3: CondMul on (line, class12) ----------------
#pragma unroll
    for (int ii = 0; ii < 8; ii++) act[ii] = x_in[(64 + 8 * s + ii) * HWSZ + base];
    cm4p<32>(w3_0 + idx3 * 1024, b3_0 + idx3 * 32, s, act, acc8);
    wb_lrelu8(act, acc8);
    cm4p<32>(w3_1 + idx3 * 1024, b3_1 + idx3 * 32, s, act, acc8);
    wb_lrelu8(act, acc8);
    cm4p<16>(w3_2 + idx3 * 512, b3_2 + idx3 * 16, s, act, acc4);
    const int i3 = argmax4(acc4, s);

    const int inds123 = min(max(inds12 * 10 + (i3 - 3), 0), 1919);

    // ---------------- regressor at predicted leaf ----------------
#pragma unroll
    for (int ii = 0; ii < 8; ii++) act[ii] = x_in[(96 + 8 * s + ii) * HWSZ + base];
    const size_t idxs = (size_t)h * 384 + (size_t)(inds123 / 5);
    cm4p<32>(wr0 + idxs * 1024, br0 + idxs * 32, s, act, acc8);
    wb_lrelu8(act, acc8);

    const size_t idxr = (size_t)h * 1920 + (size_t)inds123;
    const float* __restrict__ wr1r = wr1 + idxr * 32 + 8 * s;
    float4 wa = *reinterpret_cast<const float4*>(wr1r);
    float4 wb = *reinterpret_cast<const float4*>(wr1r + 4);
    float rpart = 0.0f;
    rpart = fmaf(act[0], wa.x, rpart); rpart = fmaf(act[1], wa.y, rpart);
    rpart = fmaf(act[2], wa.z, rpart); rpart = fmaf(act[3], wa.w, rpart);
    rpart = fmaf(act[4], wb.x, rpart); rpart = fmaf(act[5], wb.y, rpart);
    rpart = fmaf(act[6], wb.z, rpart); rpart = fmaf(act[7], wb.w, rpart);
    rpart += __shfl_xor(rpart, 1, 4);
    rpart += __shfl_xor(rpart, 2, 4);
    const float r = rpart + br1[idxr];

    if (s == 0 && valid) {
        float v = ((float)inds123 + r) * (1.0f / 1920.0f);
        out[h * WW + w] = (v - 0.1f) * 1.25f;
    }
}

extern "C" void kernel_launch(void* const* d_in, const int* in_sizes, int n_in,
                              void* d_out, int out_size, void* d_ws, size_t ws_size,
                              hipStream_t stream) {
    const float* p[23];
    for (int i = 0; i < 23; i++) p[i] = (const float*)d_in[i];
    dim3 grid(10, HH);   // 64 pixels per block, 4 lanes per pixel
    regressor_fused<<<grid, 256, 0, stream>>>(
        p[0],
        p[1], p[2], p[3], p[4], p[5], p[6],
        p[7], p[8], p[9], p[10], p[11], p[12],
        p[13], p[14], p[15], p[16], p[17], p[18],
        p[19], p[20], p[21], p[22],
        (float*)d_out);
}